// Round 10
// baseline (783.443 us; speedup 1.0000x reference)
//
#include <hip/hip_runtime.h>
#include <hip/hip_bf16.h>

typedef __attribute__((ext_vector_type(8))) short v8s;
typedef __attribute__((ext_vector_type(4))) short v4s;
typedef __attribute__((ext_vector_type(4))) float v4f;
typedef __attribute__((ext_vector_type(8))) float v8f;
typedef __attribute__((ext_vector_type(16))) float v16f;

#define NB 4
#define NN 4096
#define ND 256
#define NH 4
#define NHD 64

__device__ __forceinline__ short f2bs(float f) {
  union { __hip_bfloat16 h; short s; } u;
  u.h = __float2bfloat16(f);
  return u.s;
}
__device__ __forceinline__ float bs2f(short s) {
  union { short s; __hip_bfloat16 h; } u;
  u.s = s;
  return __bfloat162float(u.h);
}
__device__ __forceinline__ short f2bs_fast(float f) {
  unsigned u = __float_as_uint(f);
  return (short)((u + 0x7fffu + ((u >> 16) & 1u)) >> 16);
}
__device__ __forceinline__ float fexp2(float x) {
#if __has_builtin(__builtin_amdgcn_exp2f)
  return __builtin_amdgcn_exp2f(x);
#else
  return exp2f(x);
#endif
}
__device__ __forceinline__ unsigned cvt_pk(float lo, float hi) {
  unsigned r;
  asm("v_cvt_pk_bf16_f32 %0, %1, %2" : "=v"(r) : "v"(lo), "v"(hi));
  return r;
}
__device__ __forceinline__ void pl32(unsigned &a, unsigned &b) {
  asm("v_permlane32_swap_b32 %0, %1" : "+v"(a), "+v"(b));
}
__device__ __forceinline__ float xpick(float x, int hf) {
  unsigned t = __float_as_uint(x), u = t;
  pl32(t, u);
  return __uint_as_float(hf ? t : u);
}

__device__ __forceinline__ void gload16(const short* g, short* l) {
  __builtin_amdgcn_global_load_lds((const __attribute__((address_space(1))) void*)g,
                                   (__attribute__((address_space(3))) void*)l, 16, 0, 0);
}

#define VMW(n) asm volatile("s_waitcnt vmcnt(" #n ")" ::: "memory")
#define BAR()  { __builtin_amdgcn_s_barrier(); __builtin_amdgcn_sched_barrier(0); }

// ---------------- K0: cast descriptors fp32 -> bf16 into hbuf[:, 0:256] (ld 512)
__global__ void k_cast(const float* __restrict__ desc, short* __restrict__ hbuf) {
  int i = blockIdx.x * blockDim.x + threadIdx.x;
  const v4f* src = (const v4f*)desc;
  v4f v = src[i];
  int e0 = i << 2;
  int row = e0 >> 8;
  int col = e0 & 255;
  v4s o;
  #pragma unroll
  for (int j = 0; j < 4; ++j) o[j] = f2bs(v[j]);
  *(v4s*)(hbuf + row * 512 + col) = o;
}

// ---------------- K0b: cast weights fp32 -> bf16 (Wqkv | out_w | ffn1_w | ffn2_w)
__global__ void k_wcast(const float* __restrict__ a, const float* __restrict__ b,
                        const float* __restrict__ c, const float* __restrict__ d,
                        short* __restrict__ o) {
  int i = (blockIdx.x * 256 + threadIdx.x) * 8;
  const float* s; int off;
  if (i < 196608)      { s = a; off = 0; }
  else if (i < 262144) { s = b; off = 196608; }
  else if (i < 524288) { s = c; off = 262144; }
  else                 { s = d; off = 524288; }
  v8f v = *(const v8f*)(s + (i - off));
  v8s r;
  #pragma unroll
  for (int j = 0; j < 8; ++j) r[j] = f2bs(v[j]);
  *(v8s*)(o + i) = r;
}

// ---------------- K1: QKV GEMM + fused RoPE (permuted col order), gload16 dbuf staging
__global__ __launch_bounds__(256)
void k_qkv(const short* __restrict__ hbuf, const short* __restrict__ Wb,
           const float* __restrict__ bias, const float* __restrict__ kp,
           short* __restrict__ Qb, short* __restrict__ Kb, short* __restrict__ Vt) {
  __shared__ short Al[2][2048];
  __shared__ short Bl[2][2048];
  int mt = blockIdx.x, nt = blockIdx.y, tid = threadIdx.x;
  int w = tid >> 6, lane = tid & 63, lg = lane >> 4, lr = lane & 15;
  int t_ = nt >> 2, h_ = nt & 3;
  int srow = tid >> 2, sc = tid & 3;
  int scol = ((sc ^ (srow & 3)) << 3);
  int dS = (nt * 64 + srow) & 63;
  int wrow = h_ * 192 + dS * 3 + t_;
  const short* asrc = hbuf + (size_t)(mt * 64 + srow) * 512 + scol;
  const short* bsrc = Wb + (size_t)wrow * 256 + scol;
  v4f acc[4] = {};
  int ar = w * 16 + lr;
  int aoff = ar * 32 + ((lg * 8) ^ ((ar & 3) << 3));

#define G_STAGE(kt, b) do { \
    gload16(asrc + (kt) * 32, &Al[b][w * 512]); \
    gload16(bsrc + (kt) * 32, &Bl[b][w * 512]); \
  } while (0)
#define G_COMP(b) do { \
    v8s af = *(const v8s*)(&Al[b][aoff]); \
    _Pragma("unroll") \
    for (int c = 0; c < 4; ++c) { \
      int br = c * 16 + lr; \
      v8s bf = *(const v8s*)(&Bl[b][br * 32 + ((lg * 8) ^ ((br & 3) << 3))]); \
      acc[c] = __builtin_amdgcn_mfma_f32_16x16x32_bf16(af, bf, acc[c], 0, 0, 0); \
    } \
  } while (0)

  G_STAGE(0, 0);
  #pragma unroll 1
  for (int k2 = 0; k2 < 4; ++k2) {
    int kt = k2 * 2;
    G_STAGE(kt + 1, 1);
    VMW(2); BAR();
    G_COMP(0);
    BAR();
    if (kt + 2 < 8) { G_STAGE(kt + 2, 0); VMW(2); } else { VMW(0); }
    BAR();
    G_COMP(1);
    BAR();
  }
#undef G_STAGE
#undef G_COMP

  int grow0 = mt * 64 + w * 16 + lg * 4;
  int b_ = grow0 >> 12, n0 = grow0 & 4095;
  if (t_ == 2) {
    #pragma unroll
    for (int c = 0; c < 4; ++c) {
      int d = c * 16 + lr;
      float bb = bias[h_ * 192 + d * 3 + 2];
      v4s pw;
      #pragma unroll
      for (int j = 0; j < 4; ++j) pw[j] = f2bs(acc[c][j] + bb);
      *(v4s*)(Vt + ((size_t)((b_ * NH + h_) * NHD + d) * NN + n0)) = pw;
    }
  } else {
    float qsc = (t_ == 0) ? 0.125f * 1.44269504088896340736f : 1.0f;
    short* dst = (t_ == 0) ? Qb : Kb;
    #pragma unroll
    for (int c = 0; c < 4; ++c) {
      int d = c * 16 + lr;
      float bb = bias[h_ * 192 + d * 3 + t_];
      #pragma unroll
      for (int j = 0; j < 4; ++j) {
        float x = acc[c][j] + bb;
        float xp = __shfl_xor(x, 1, 64);
        int n_ = n0 + j;
        float cs = kp[((size_t)b_ * NN + n_) * 64 + d];
        float sn = kp[((size_t)(NB + b_) * NN + n_) * 64 + d];
        float ov = (d & 1) ? (x * cs + xp * sn) : (x * cs - xp * sn);
        dst[((size_t)((b_ * NH + h_) * NN + n_)) * 64 + d] = f2bs(ov * qsc);
      }
    }
  }
}

// ---------------- K3: flash attention v10. grid (16,16,4), 512 threads = 8 waves, 32KB LDS.
// Block z handles kv quarter [z*1024,(z+1)*1024); 4 blocks/CU co-resident (32 waves/CU).
// Writes unnormalized bf16 partial O + fp32 (M,L); k_amerge does 4-way merge.
__global__ __launch_bounds__(512, 8)
void k_attn(const short* __restrict__ Qb, const short* __restrict__ Kb,
            const short* __restrict__ Vt, short* __restrict__ pO,
            float* __restrict__ pm, float* __restrict__ pl) {
  __shared__ short Kl[2][4096];
  __shared__ short Vl[2][4096];
  int qt = blockIdx.x, bh = blockIdx.y, z = blockIdx.z;
  const short* Qp = Qb + (size_t)bh * NN * NHD;
  const short* Kp = Kb + (size_t)bh * NN * NHD;
  const short* Vp = Vt + (size_t)bh * NHD * NN;
  int tid = threadIdx.x, w = tid >> 6, lane = tid & 63;
  int q31 = lane & 31, hf = lane >> 5;
  const float THR = 11.5416f;

  v8s qf[4];
  {
    int qrow = qt * 256 + w * 32 + q31;
    #pragma unroll
    for (int kd = 0; kd < 4; ++kd)
      qf[kd] = *(const v8s*)(Qp + (size_t)qrow * 64 + kd * 16 + hf * 8);
  }
  float m = -3.0e38f, ls = 0.f;
  v16f acc[2] = {};

  int slot = w * 64 + lane;
  int r0 = slot >> 3, c0 = slot & 7;
  int ko0 = r0 * 64 + ((c0 ^ (r0 & 7)) << 3);
  size_t vo0 = (size_t)r0 * NN + ((c0 ^ (r0 & 7)) << 3);
  int tb = z * 16;
  const short* kbase = (const short*)Kl;
  const short* vbase = (const short*)Vl;

  #define STAGE(t, bfi) do { \
    gload16(Kp + (size_t)(t) * 4096 + ko0, (short*)Kl + (bfi) * 4096 + w * 512); \
    gload16(Vp + (size_t)(t) * 64 + vo0, (short*)Vl + (bfi) * 4096 + w * 512); \
  } while (0)

  #define ATILE(BOFS) do { \
    v16f st[2]; \
    __builtin_amdgcn_s_setprio(1); \
    _Pragma("unroll") \
    for (int kvb = 0; kvb < 2; ++kvb) { \
      int r = kvb * 32 + q31; \
      int sw = r & 7; \
      v16f zz = {}; \
      _Pragma("unroll") \
      for (int kd = 0; kd < 4; ++kd) { \
        v8s kf = *(const v8s*)(kbase + (BOFS) + r * 64 + (((kd * 2 + hf) ^ sw) << 3)); \
        zz = __builtin_amdgcn_mfma_f32_32x32x16_bf16(kf, qf[kd], zz, 0, 0, 0); \
      } \
      st[kvb] = zz; \
    } \
    __builtin_amdgcn_s_setprio(0); \
    float mx[8]; \
    _Pragma("unroll") \
    for (int i = 0; i < 8; ++i) \
      mx[i] = fmaxf(fmaxf(st[0][i], st[0][i + 8]), fmaxf(st[1][i], st[1][i + 8])); \
    _Pragma("unroll") \
    for (int off = 4; off >= 1; off >>= 1) \
      _Pragma("unroll") \
      for (int i = 0; i < off; ++i) mx[i] = fmaxf(mx[i], mx[i + off]); \
    float pmax = fmaxf(mx[0], xpick(mx[0], hf)); \
    if (__any(pmax - m > THR)) { \
      float mn = fmaxf(m, pmax); \
      float rr = fexp2(m - mn); \
      m = mn; \
      _Pragma("unroll") \
      for (int db = 0; db < 2; ++db) \
        _Pragma("unroll") \
        for (int r = 0; r < 16; ++r) acc[db][r] *= rr; \
      ls *= rr; \
    } \
    _Pragma("unroll") \
    for (int kvb = 0; kvb < 2; ++kvb) \
      _Pragma("unroll") \
      for (int r = 0; r < 16; ++r) st[kvb][r] = fexp2(st[kvb][r] - m); \
    float sm[8]; \
    _Pragma("unroll") \
    for (int i = 0; i < 8; ++i) \
      sm[i] = (st[0][i] + st[0][i + 8]) + (st[1][i] + st[1][i + 8]); \
    _Pragma("unroll") \
    for (int off = 4; off >= 1; off >>= 1) \
      _Pragma("unroll") \
      for (int i = 0; i < off; ++i) sm[i] += sm[i + off]; \
    ls += sm[0] + xpick(sm[0], hf); \
    __builtin_amdgcn_s_setprio(1); \
    _Pragma("unroll") \
    for (int s = 0; s < 4; ++s) { \
      int kvb = s >> 1, rb = (s & 1) * 8; \
      unsigned u0 = cvt_pk(st[kvb][rb + 0], st[kvb][rb + 1]); \
      unsigned u1 = cvt_pk(st[kvb][rb + 2], st[kvb][rb + 3]); \
      unsigned u2 = cvt_pk(st[kvb][rb + 4], st[kvb][rb + 5]); \
      unsigned u3 = cvt_pk(st[kvb][rb + 6], st[kvb][rb + 7]); \
      pl32(u0, u2); \
      pl32(u1, u3); \
      union { unsigned u[4]; v8s v; } pf; \
      pf.u[0] = u0; pf.u[1] = u1; pf.u[2] = u2; pf.u[3] = u3; \
      _Pragma("unroll") \
      for (int db = 0; db < 2; ++db) { \
        int r = db * 32 + q31; \
        v8s vf = *(const v8s*)(vbase + (BOFS) + r * 64 + (((s * 2 + hf) ^ (r & 7)) << 3)); \
        acc[db] = __builtin_amdgcn_mfma_f32_32x32x16_bf16(vf, pf.v, acc[db], 0, 0, 0); \
      } \
    } \
    __builtin_amdgcn_s_setprio(0); \
  } while (0)

  STAGE(tb, 0);
  #pragma unroll 1
  for (int k2 = 0; k2 < 8; ++k2) {
    int kt = k2 * 2;
    STAGE(tb + kt + 1, 1);
    VMW(2); BAR();
    ATILE(0);
    BAR();
    if (kt + 2 < 16) { STAGE(tb + kt + 2, 0); VMW(2); } else { VMW(0); }
    BAR();
    ATILE(4096);
    BAR();
  }
  #undef STAGE
  #undef ATILE

  // ---- write unnormalized partial O + (M, L) ----
  int rowg = ((z * 16 + bh) << 12) + qt * 256 + w * 32 + q31;
  #pragma unroll
  for (int db = 0; db < 2; ++db)
    #pragma unroll
    for (int r4 = 0; r4 < 4; ++r4) {
      v4s o;
      #pragma unroll
      for (int j = 0; j < 4; ++j) o[j] = f2bs(acc[db][r4 * 4 + j]);
      *(v4s*)(pO + (size_t)rowg * 64 + db * 32 + r4 * 8 + hf * 4) = o;
    }
  if (hf == 0) { pm[rowg] = m; pl[rowg] = ls; }
}

// ---------------- K3b: 4-way merge of kv-quarter partials -> ctx bf16
__global__ __launch_bounds__(256)
void k_amerge(const short* __restrict__ pO, const float* __restrict__ pm,
              const float* __restrict__ pl, short* __restrict__ ctx) {
  int idx = blockIdx.x * 256 + threadIdx.x;   // 524288 total
  int row = idx >> 3, c8 = (idx & 7) * 8;
  int bh = row >> 12, n = row & 4095;
  int b = bh >> 2, h = bh & 3;
  float mz[4], lz[4];
  #pragma unroll
  for (int z = 0; z < 4; ++z) { mz[z] = pm[z * 65536 + row]; lz[z] = pl[z * 65536 + row]; }
  float M = fmaxf(fmaxf(mz[0], mz[1]), fmaxf(mz[2], mz[3]));
  float wz[4], L = 0.f;
  #pragma unroll
  for (int z = 0; z < 4; ++z) { wz[z] = fexp2(mz[z] - M); L += lz[z] * wz[z]; }
  float rc = 1.0f / L;
  float a[8] = {};
  #pragma unroll
  for (int z = 0; z < 4; ++z) {
    v8s p = *(const v8s*)(pO + ((size_t)(z * 65536 + row)) * 64 + c8);
    #pragma unroll
    for (int j = 0; j < 8; ++j) a[j] += bs2f(p[j]) * wz[z];
  }
  v8s o;
  #pragma unroll
  for (int j = 0; j < 8; ++j) o[j] = f2bs(a[j] * rc);
  *(v8s*)(ctx + (size_t)(b * NN + n) * ND + h * 64 + c8) = o;
}

// ---------------- K4: out-proj GEMM (M=16384,K=256,N=256) -> hbuf[:, 256:512]
__global__ __launch_bounds__(256)
void k_oproj(const short* __restrict__ ctx, const short* __restrict__ Wb,
             const float* __restrict__ bias, short* __restrict__ hbuf) {
  __shared__ short Al[2][2048];
  __shared__ short Bl[2][2048];
  int mt = blockIdx.x, nt = blockIdx.y, tid = threadIdx.x;
  int w = tid >> 6, lane = tid & 63, lg = lane >> 4, lr = lane & 15;
  int srow = tid >> 2, sc = tid & 3;
  int scol = ((sc ^ (srow & 3)) << 3);
  const short* asrc = ctx + (size_t)(mt * 64 + srow) * 256 + scol;
  const short* bsrc = Wb + (size_t)(nt * 64 + srow) * 256 + scol;
  v4f acc[4] = {};
  int ar = w * 16 + lr;
  int aoff = ar * 32 + ((lg * 8) ^ ((ar & 3) << 3));

#define G_STAGE(kt, b) do { \
    gload16(asrc + (kt) * 32, &Al[b][w * 512]); \
    gload16(bsrc + (kt) * 32, &Bl[b][w * 512]); \
  } while (0)
#define G_COMP(b) do { \
    v8s af = *(const v8s*)(&Al[b][aoff]); \
    _Pragma("unroll") \
    for (int c = 0; c < 4; ++c) { \
      int br = c * 16 + lr; \
      v8s bf = *(const v8s*)(&Bl[b][br * 32 + ((lg * 8) ^ ((br & 3) << 3))]); \
      acc[c] = __builtin_amdgcn_mfma_f32_16x16x32_bf16(af, bf, acc[c], 0, 0, 0); \
    } \
  } while (0)

  G_STAGE(0, 0);
  #pragma unroll 1
  for (int k2 = 0; k2 < 4; ++k2) {
    int kt = k2 * 2;
    G_STAGE(kt + 1, 1);
    VMW(2); BAR();
    G_COMP(0);
    BAR();
    if (kt + 2 < 8) { G_STAGE(kt + 2, 0); VMW(2); } else { VMW(0); }
    BAR();
    G_COMP(1);
    BAR();
  }
#undef G_STAGE
#undef G_COMP

  #pragma unroll
  for (int c = 0; c < 4; ++c) {
    int gcol = nt * 64 + c * 16 + lr;
    float bb = bias[gcol];
    #pragma unroll
    for (int j = 0; j < 4; ++j) {
      int grow = mt * 64 + w * 16 + lg * 4 + j;
      hbuf[(size_t)grow * 512 + 256 + gcol] = f2bs(acc[c][j] + bb);
    }
  }
}

// ---------------- K5: ffn1 v2: 8 waves, 64x512/block, swapped-operand MFMA + cheap LN
__global__ __launch_bounds__(512)
void k_ffn1(const short* __restrict__ hbuf, const short* __restrict__ Wb,
            const float* __restrict__ bias, const float* __restrict__ ln_g,
            const float* __restrict__ ln_b, short* __restrict__ h2) {
  __shared__ short Al[2][2048];
  __shared__ short Bl[2][16384];
  __shared__ float red[64][16];
  int mt = blockIdx.x, tid = threadIdx.x;
  int w = tid >> 6, lane = tid & 63, lg = lane >> 4, lr = lane & 15;
  int srow = tid >> 2, sc = tid & 3;
  int scol = ((sc ^ (srow & 3)) << 3);
  const short* asrc = hbuf + (size_t)(mt * 64 + srow) * 512 + scol;
  const short* bsrc = Wb + (size_t)srow * 512 + scol;
  v4f acc[4][4] = {};

#define F1_STAGE(kt, b) do { \
    if (w < 4) gload16(asrc + (kt) * 32, &Al[b][w * 512]); \
    _Pragma("unroll") \
    for (int i = 0; i < 4; ++i) \
      gload16(bsrc + (size_t)i * 65536 + (kt) * 32, &Bl[b][i * 4096 + w * 512]); \
  } while (0)
#define F1_VMW() do { \
    if (w < 4) { asm volatile("s_waitcnt vmcnt(5)" ::: "memory"); } \
    else       { asm volatile("s_waitcnt vmcnt(4)" ::: "memory"); } \
  } while (0)
#define F1_COMP(b) do { \
    v8s af[4]; \
    _Pragma("unroll") \
    for (int mi = 0; mi < 4; ++mi) { \
      int ar = mi * 16 + lr; \
      af[mi] = *(const v8s*)(&Al[b][ar * 32 + ((lg * 8) ^ ((ar & 3) << 3))]); \
    } \
    _Pragma("unroll") \
    for (int ni = 0; ni < 4; ++ni) { \
      int br = w * 64 + ni * 16 + lr; \
      v8s bf = *(const v8s*)(&Bl[b][br * 32 + ((lg * 8) ^ ((br & 3) << 3))]); \
      _Pragma("unroll") \
      for (int mi = 0; mi < 4; ++mi) \
        acc[mi][ni] = __builtin_amdgcn_mfma_f32_16x16x32_bf16(bf, af[mi], acc[mi][ni], 0, 0, 0); \
    } \
  } while (0)

  F1_STAGE(0, 0);
  #pragma unroll 1
  for (int k2 = 0; k2 < 8; ++k2) {
    int kt = k2 * 2;
    F1_STAGE(kt + 1, 1);
    F1_VMW(); BAR();
    F1_COMP(0);
    BAR();
    if (kt + 2 < 16) { F1_STAGE(kt + 2, 0); F1_VMW(); } else { VMW(0); }
    BAR();
    F1_COMP(1);
    BAR();
  }
#undef F1_STAGE
#undef F1_VMW
#undef F1_COMP

  #pragma unroll
  for (int ni = 0; ni < 4; ++ni) {
    v4f bb = *(const v4f*)(bias + w * 64 + ni * 16 + lg * 4);
    #pragma unroll
    for (int mi = 0; mi < 4; ++mi)
      #pragma unroll
      for (int j = 0; j < 4; ++j) acc[mi][ni][j] += bb[j];
  }
  float ps[4], qs[4];
  #pragma unroll
  for (int mi = 0; mi < 4; ++mi) {
    float p = 0.f, q = 0.f;
    #pragma unroll
    for (int ni = 0; ni < 4; ++ni)
      #pragma unroll
      for (int j = 0; j < 4; ++j) { float v = acc[mi][ni][j]; p += v; q += v * v; }
    p += __shfl_xor(p, 16, 64); q += __shfl_xor(q, 16, 64);
    p += __shfl_xor(p, 32, 64); q += __shfl_xor(q, 32, 64);
    ps[mi] = p; qs[mi] = q;
  }
  if (lane < 16) {
    #pragma unroll
    for (int mi = 0; mi < 4; ++mi) {
      red[mi * 16 + lane][w * 2] = ps[mi];
      red[mi * 16 + lane][w * 2 + 1] = qs[mi];
    }
  }
  __syncthreads();
  float mus[4], rss[4];
  #pragma unroll
  for (int mi = 0; mi < 4; ++mi) {
    int row = mi * 16 + lr;
    v4f r0 = *(const v4f*)&red[row][0];
    v4f r1 = *(const v4f*)&red[row][4];
    v4f r2 = *(const v4f*)&red[row][8];
    v4f r3 = *(const v4f*)&red[row][12];
    float sum = r0[0] + r0[2] + r1[0] + r1[2] + r2[0] + r2[2] + r3[0] + r3[2];
    float sq  = r0[1] + r0[3] + r1[1] + r1[3] + r2[1] + r2[3] + r3[1] + r3[3];
    float mu = sum * (1.0f / 512.0f);
    float var = sq * (1.0f / 512.0f) - mu * mu;
    mus[mi] = mu;
    rss[mi] = rsqrtf(var + 1e-5f);
  }
  #pragma unroll
  for (int ni = 0; ni < 4; ++ni) {
    int cb = w * 64 + ni * 16 + lg * 4;
    v4f g4 = *(const v4f*)(ln_g + cb);
    v4f b4 = *(const v4f*)(ln_b + cb);
    #pragma unroll
    for (int mi = 0; mi < 4; ++mi) {
      int grow = mt * 64 + mi * 16 + lr;
      v4s o;
      #pragma unroll
      for (int j = 0; j < 4; ++j) {
        float y = (acc[mi][ni][j] - mus[mi]) * rss[mi] * g4[j] + b4[j];
        float z = 0.7978845608f * (y + 0.044715f * y * y * y);
        float e = fexp2(2.88539008178f * z);
        float t = (e - 1.0f) * __builtin_amdgcn_rcpf(e + 1.0f);
        o[j] = f2bs_fast(0.5f * y * (1.0f + t));
      }
      *(v4s*)(h2 + (size_t)grow * 512 + cb) = o;
    }
  }
}

// ---------------- K6: ffn2 GEMM (M=16384,K=512,N=256) + bias + residual -> out fp32
__global__ __launch_bounds__(256)
void k_ffn2(const short* __restrict__ h2, const short* __restrict__ Wb,
             const float* __restrict__ bias, const float* __restrict__ desc,
             float* __restrict__ out) {
  __shared__ short Al[2][2048];
  __shared__ short Bl[2][2048];
  int mt = blockIdx.x, nt = blockIdx.y, tid = threadIdx.x;
  int w = tid >> 6, lane = tid & 63, lg = lane >> 4, lr = lane & 15;
  int srow = tid >> 2, sc = tid & 3;
  int scol = ((sc ^ (srow & 3)) << 3);
  const short* asrc = h2 + (size_t)(mt * 64 + srow) * 512 + scol;
  const short* bsrc = Wb + (size_t)(nt * 64 + srow) * 512 + scol;
  v4f acc[4] = {};
  int ar = w * 16 + lr;
  int aoff = ar * 32 + ((lg * 8) ^ ((ar & 3) << 3));

#define G_STAGE(kt, b) do { \
    gload16(asrc + (kt) * 32, &Al[b][w * 512]); \
    gload16(bsrc + (kt) * 32, &Bl[b][w * 512]); \
  } while (0)
#define G_COMP(b) do { \
    v8s af = *(const v8s*)(&Al[b][aoff]); \
    _Pragma("unroll") \
    for (int c = 0; c < 4; ++c) { \
      int br = c * 16 + lr; \
      v8s bf = *(const v8s*)(&Bl[b][br * 32 + ((lg * 8) ^ ((br & 3) << 3))]); \
      acc[c] = __builtin_amdgcn_mfma_f32_16x16x32_bf16(af, bf, acc[c], 0, 0, 0); \
    } \
  } while (0)

  G_STAGE(0, 0);
  #pragma unroll 1
  for (int k2 = 0; k2 < 8; ++k2) {
    int kt = k2 * 2;
    G_STAGE(kt + 1, 1);
    VMW(2); BAR();
    G_COMP(0);
    BAR();
    if (kt + 2 < 16) { G_STAGE(kt + 2, 0); VMW(2); } else { VMW(0); }
    BAR();
    G_COMP(1);
    BAR();
  }
#undef G_STAGE
#undef G_COMP

  #pragma unroll
  for (int c = 0; c < 4; ++c) {
    int gcol = nt * 64 + c * 16 + lr;
    float bb = bias[gcol];
    #pragma unroll
    for (int j = 0; j < 4; ++j) {
      int grow = mt * 64 + w * 16 + lg * 4 + j;
      out[(size_t)grow * 256 + gcol] = desc[(size_t)grow * 256 + gcol] + acc[c][j] + bb;
    }
  }
}

extern "C" void kernel_launch(void* const* d_in, const int* in_sizes, int n_in,
                              void* d_out, int out_size, void* d_ws, size_t ws_size,
                              hipStream_t stream) {
  const float* desc   = (const float*)d_in[0];
  const float* kp     = (const float*)d_in[1];
  const float* Wqkv_w = (const float*)d_in[2];
  const float* Wqkv_b = (const float*)d_in[3];
  const float* out_w  = (const float*)d_in[4];
  const float* out_b  = (const float*)d_in[5];
  const float* ffn1_w = (const float*)d_in[6];
  const float* ffn1_b = (const float*)d_in[7];
  const float* ln_g   = (const float*)d_in[8];
  const float* ln_b   = (const float*)d_in[9];
  const float* ffn2_w = (const float*)d_in[10];
  const float* ffn2_b = (const float*)d_in[11];
  float* out = (float*)d_out;
  char* ws = (char*)d_ws;

  const size_t MB = 1024 * 1024;
  short* hbuf = (short*)(ws);                 // [16384][512] bf16 (desc | message)
  short* Qb   = (short*)(ws + 16 * MB);       // [B,H,N,64]
  short* Kb   = (short*)(ws + 24 * MB);
  short* Vt   = (short*)(ws + 32 * MB);       // [B,H,64,N] (transposed V)
  short* ctxb = (short*)(ws + 40 * MB);       // [16384][256]
  short* h2   = (short*)(ws + 16 * MB);       // reuses Qb/Kb (dead after attn)
  short* wbuf = (short*)(ws + 48 * MB);       // bf16 weights: 1.25MB
  short* wq = wbuf;                           // [768][256]
  short* wo = wbuf + 196608;                  // [256][256]
  short* w1 = wbuf + 262144;                  // [512][512]
  short* w2 = wbuf + 524288;                  // [256][512]
  short* pO = (short*)(ws + 50 * MB);         // [4][16][4096][64] bf16 partial O : 32MB
  float* pm = (float*)(ws + 82 * MB);         // [4][65536] fp32 : 1MB
  float* pl = (float*)(ws + 83 * MB);         // [4][65536] fp32 : 1MB

  k_wcast <<<dim3(320),        dim3(256), 0, stream>>>(Wqkv_w, out_w, ffn1_w, ffn2_w, wbuf);
  k_cast  <<<dim3(4096),       dim3(256), 0, stream>>>(desc, hbuf);
  k_qkv   <<<dim3(256, 12),    dim3(256), 0, stream>>>(hbuf, wq, Wqkv_b, kp, Qb, Kb, Vt);
  k_attn  <<<dim3(16, 16, 4),  dim3(512), 0, stream>>>(Qb, Kb, Vt, pO, pm, pl);
  k_amerge<<<dim3(2048),       dim3(256), 0, stream>>>(pO, pm, pl, ctxb);
  k_oproj <<<dim3(256, 4),     dim3(256), 0, stream>>>(ctxb, wo, out_b, hbuf);
  k_ffn1  <<<dim3(256),        dim3(512), 0, stream>>>(hbuf, w1, ffn1_b, ln_g, ln_b, h2);
  k_ffn2  <<<dim3(256, 4),     dim3(256), 0, stream>>>(h2, w2, ffn2_b, desc, out);
}

// Round 11
// 170.304 us; speedup vs baseline: 4.6003x; 4.6003x over previous
//
#include <hip/hip_runtime.h>
#include <hip/hip_bf16.h>

typedef __attribute__((ext_vector_type(8))) short v8s;
typedef __attribute__((ext_vector_type(4))) short v4s;
typedef __attribute__((ext_vector_type(4))) float v4f;
typedef __attribute__((ext_vector_type(8))) float v8f;
typedef __attribute__((ext_vector_type(16))) float v16f;

#define NB 4
#define NN 4096
#define ND 256
#define NH 4
#define NHD 64

__device__ __forceinline__ short f2bs(float f) {
  union { __hip_bfloat16 h; short s; } u;
  u.h = __float2bfloat16(f);
  return u.s;
}
__device__ __forceinline__ float bs2f(short s) {
  union { short s; __hip_bfloat16 h; } u;
  u.s = s;
  return __bfloat162float(u.h);
}
__device__ __forceinline__ short f2bs_fast(float f) {
  unsigned u = __float_as_uint(f);
  return (short)((u + 0x7fffu + ((u >> 16) & 1u)) >> 16);
}
__device__ __forceinline__ float fexp2(float x) {
#if __has_builtin(__builtin_amdgcn_exp2f)
  return __builtin_amdgcn_exp2f(x);
#else
  return exp2f(x);
#endif
}
__device__ __forceinline__ unsigned cvt_pk(float lo, float hi) {
  unsigned r;
  asm("v_cvt_pk_bf16_f32 %0, %1, %2" : "=v"(r) : "v"(lo), "v"(hi));
  return r;
}
__device__ __forceinline__ void pl32(unsigned &a, unsigned &b) {
  asm("v_permlane32_swap_b32 %0, %1" : "+v"(a), "+v"(b));
}
__device__ __forceinline__ float xpick(float x, int hf) {
  unsigned t = __float_as_uint(x), u = t;
  pl32(t, u);
  return __uint_as_float(hf ? t : u);
}

__device__ __forceinline__ void gload16(const short* g, short* l) {
  __builtin_amdgcn_global_load_lds((const __attribute__((address_space(1))) void*)g,
                                   (__attribute__((address_space(3))) void*)l, 16, 0, 0);
}

#define VMW(n) asm volatile("s_waitcnt vmcnt(" #n ")" ::: "memory")
#define BAR()  { __builtin_amdgcn_s_barrier(); __builtin_amdgcn_sched_barrier(0); }

// ---------------- K0: cast descriptors fp32 -> bf16 into hbuf[:, 0:256] (ld 512)
__global__ void k_cast(const float* __restrict__ desc, short* __restrict__ hbuf) {
  int i = blockIdx.x * blockDim.x + threadIdx.x;
  const v4f* src = (const v4f*)desc;
  v4f v = src[i];
  int e0 = i << 2;
  int row = e0 >> 8;
  int col = e0 & 255;
  v4s o;
  #pragma unroll
  for (int j = 0; j < 4; ++j) o[j] = f2bs(v[j]);
  *(v4s*)(hbuf + row * 512 + col) = o;
}

// ---------------- K0b: cast weights fp32 -> bf16 (Wqkv | out_w | ffn1_w | ffn2_w)
__global__ void k_wcast(const float* __restrict__ a, const float* __restrict__ b,
                        const float* __restrict__ c, const float* __restrict__ d,
                        short* __restrict__ o) {
  int i = (blockIdx.x * 256 + threadIdx.x) * 8;
  const float* s; int off;
  if (i < 196608)      { s = a; off = 0; }
  else if (i < 262144) { s = b; off = 196608; }
  else if (i < 524288) { s = c; off = 262144; }
  else                 { s = d; off = 524288; }
  v8f v = *(const v8f*)(s + (i - off));
  v8s r;
  #pragma unroll
  for (int j = 0; j < 8; ++j) r[j] = f2bs(v[j]);
  *(v8s*)(o + i) = r;
}

// ---------------- K1: QKV GEMM + fused RoPE (permuted col order), gload16 dbuf staging
__global__ __launch_bounds__(256)
void k_qkv(const short* __restrict__ hbuf, const short* __restrict__ Wb,
           const float* __restrict__ bias, const float* __restrict__ kp,
           short* __restrict__ Qb, short* __restrict__ Kb, short* __restrict__ Vt) {
  __shared__ short Al[2][2048];
  __shared__ short Bl[2][2048];
  int mt = blockIdx.x, nt = blockIdx.y, tid = threadIdx.x;
  int w = tid >> 6, lane = tid & 63, lg = lane >> 4, lr = lane & 15;
  int t_ = nt >> 2, h_ = nt & 3;
  int srow = tid >> 2, sc = tid & 3;
  int scol = ((sc ^ (srow & 3)) << 3);
  int dS = (nt * 64 + srow) & 63;
  int wrow = h_ * 192 + dS * 3 + t_;
  const short* asrc = hbuf + (size_t)(mt * 64 + srow) * 512 + scol;
  const short* bsrc = Wb + (size_t)wrow * 256 + scol;
  v4f acc[4] = {};
  int ar = w * 16 + lr;
  int aoff = ar * 32 + ((lg * 8) ^ ((ar & 3) << 3));

#define G_STAGE(kt, b) do { \
    gload16(asrc + (kt) * 32, &Al[b][w * 512]); \
    gload16(bsrc + (kt) * 32, &Bl[b][w * 512]); \
  } while (0)
#define G_COMP(b) do { \
    v8s af = *(const v8s*)(&Al[b][aoff]); \
    _Pragma("unroll") \
    for (int c = 0; c < 4; ++c) { \
      int br = c * 16 + lr; \
      v8s bf = *(const v8s*)(&Bl[b][br * 32 + ((lg * 8) ^ ((br & 3) << 3))]); \
      acc[c] = __builtin_amdgcn_mfma_f32_16x16x32_bf16(af, bf, acc[c], 0, 0, 0); \
    } \
  } while (0)

  G_STAGE(0, 0);
  #pragma unroll 1
  for (int k2 = 0; k2 < 4; ++k2) {
    int kt = k2 * 2;
    G_STAGE(kt + 1, 1);
    VMW(2); BAR();
    G_COMP(0);
    BAR();
    if (kt + 2 < 8) { G_STAGE(kt + 2, 0); VMW(2); } else { VMW(0); }
    BAR();
    G_COMP(1);
    BAR();
  }
#undef G_STAGE
#undef G_COMP

  int grow0 = mt * 64 + w * 16 + lg * 4;
  int b_ = grow0 >> 12, n0 = grow0 & 4095;
  if (t_ == 2) {
    #pragma unroll
    for (int c = 0; c < 4; ++c) {
      int d = c * 16 + lr;
      float bb = bias[h_ * 192 + d * 3 + 2];
      v4s pw;
      #pragma unroll
      for (int j = 0; j < 4; ++j) pw[j] = f2bs(acc[c][j] + bb);
      *(v4s*)(Vt + ((size_t)((b_ * NH + h_) * NHD + d) * NN + n0)) = pw;
    }
  } else {
    float qsc = (t_ == 0) ? 0.125f * 1.44269504088896340736f : 1.0f;
    short* dst = (t_ == 0) ? Qb : Kb;
    #pragma unroll
    for (int c = 0; c < 4; ++c) {
      int d = c * 16 + lr;
      float bb = bias[h_ * 192 + d * 3 + t_];
      #pragma unroll
      for (int j = 0; j < 4; ++j) {
        float x = acc[c][j] + bb;
        float xp = __shfl_xor(x, 1, 64);
        int n_ = n0 + j;
        float cs = kp[((size_t)b_ * NN + n_) * 64 + d];
        float sn = kp[((size_t)(NB + b_) * NN + n_) * 64 + d];
        float ov = (d & 1) ? (x * cs + xp * sn) : (x * cs - xp * sn);
        dst[((size_t)((b_ * NH + h_) * NN + n_)) * 64 + d] = f2bs(ov * qsc);
      }
    }
  }
}

// ---------------- K3: flash attention v11. grid (16,16,2), 512 threads = 8 waves, 32KB LDS.
// launch_bounds(512,4) -> 128-VGPR cap (body ~95, no spill); 2 blocks/CU co-resident,
// independent barrier domains. Block z does kv half [z*2048,(z+1)*2048) = 32 tiles.
__global__ __launch_bounds__(512, 4)
void k_attn(const short* __restrict__ Qb, const short* __restrict__ Kb,
            const short* __restrict__ Vt, short* __restrict__ pO,
            float* __restrict__ pm, float* __restrict__ pl) {
  __shared__ short Kl[2][4096];
  __shared__ short Vl[2][4096];
  int qt = blockIdx.x, bh = blockIdx.y, z = blockIdx.z;
  const short* Qp = Qb + (size_t)bh * NN * NHD;
  const short* Kp = Kb + (size_t)bh * NN * NHD;
  const short* Vp = Vt + (size_t)bh * NHD * NN;
  int tid = threadIdx.x, w = tid >> 6, lane = tid & 63;
  int q31 = lane & 31, hf = lane >> 5;
  const float THR = 11.5416f;

  v8s qf[4];
  {
    int qrow = qt * 256 + w * 32 + q31;
    #pragma unroll
    for (int kd = 0; kd < 4; ++kd)
      qf[kd] = *(const v8s*)(Qp + (size_t)qrow * 64 + kd * 16 + hf * 8);
  }
  float m = -3.0e38f, ls = 0.f;
  v16f acc[2] = {};

  int slot = w * 64 + lane;
  int r0 = slot >> 3, c0 = slot & 7;
  int ko0 = r0 * 64 + ((c0 ^ (r0 & 7)) << 3);
  size_t vo0 = (size_t)r0 * NN + ((c0 ^ (r0 & 7)) << 3);
  int tb = z * 32;
  const short* kbase = (const short*)Kl;
  const short* vbase = (const short*)Vl;

  #define STAGE(t, bfi) do { \
    gload16(Kp + (size_t)(t) * 4096 + ko0, (short*)Kl + (bfi) * 4096 + w * 512); \
    gload16(Vp + (size_t)(t) * 64 + vo0, (short*)Vl + (bfi) * 4096 + w * 512); \
  } while (0)

  #define ATILE(BOFS) do { \
    v16f st[2]; \
    __builtin_amdgcn_s_setprio(1); \
    _Pragma("unroll") \
    for (int kvb = 0; kvb < 2; ++kvb) { \
      int r = kvb * 32 + q31; \
      int sw = r & 7; \
      v16f zz = {}; \
      _Pragma("unroll") \
      for (int kd = 0; kd < 4; ++kd) { \
        v8s kf = *(const v8s*)(kbase + (BOFS) + r * 64 + (((kd * 2 + hf) ^ sw) << 3)); \
        zz = __builtin_amdgcn_mfma_f32_32x32x16_bf16(kf, qf[kd], zz, 0, 0, 0); \
      } \
      st[kvb] = zz; \
    } \
    __builtin_amdgcn_s_setprio(0); \
    float mx[8]; \
    _Pragma("unroll") \
    for (int i = 0; i < 8; ++i) \
      mx[i] = fmaxf(fmaxf(st[0][i], st[0][i + 8]), fmaxf(st[1][i], st[1][i + 8])); \
    _Pragma("unroll") \
    for (int off = 4; off >= 1; off >>= 1) \
      _Pragma("unroll") \
      for (int i = 0; i < off; ++i) mx[i] = fmaxf(mx[i], mx[i + off]); \
    float pmax = fmaxf(mx[0], xpick(mx[0], hf)); \
    if (__any(pmax - m > THR)) { \
      float mn = fmaxf(m, pmax); \
      float rr = fexp2(m - mn); \
      m = mn; \
      _Pragma("unroll") \
      for (int db = 0; db < 2; ++db) \
        _Pragma("unroll") \
        for (int r = 0; r < 16; ++r) acc[db][r] *= rr; \
      ls *= rr; \
    } \
    _Pragma("unroll") \
    for (int kvb = 0; kvb < 2; ++kvb) \
      _Pragma("unroll") \
      for (int r = 0; r < 16; ++r) st[kvb][r] = fexp2(st[kvb][r] - m); \
    float sm[8]; \
    _Pragma("unroll") \
    for (int i = 0; i < 8; ++i) \
      sm[i] = (st[0][i] + st[0][i + 8]) + (st[1][i] + st[1][i + 8]); \
    _Pragma("unroll") \
    for (int off = 4; off >= 1; off >>= 1) \
      _Pragma("unroll") \
      for (int i = 0; i < off; ++i) sm[i] += sm[i + off]; \
    ls += sm[0] + xpick(sm[0], hf); \
    __builtin_amdgcn_s_setprio(1); \
    _Pragma("unroll") \
    for (int s = 0; s < 4; ++s) { \
      int kvb = s >> 1, rb = (s & 1) * 8; \
      unsigned u0 = cvt_pk(st[kvb][rb + 0], st[kvb][rb + 1]); \
      unsigned u1 = cvt_pk(st[kvb][rb + 2], st[kvb][rb + 3]); \
      unsigned u2 = cvt_pk(st[kvb][rb + 4], st[kvb][rb + 5]); \
      unsigned u3 = cvt_pk(st[kvb][rb + 6], st[kvb][rb + 7]); \
      pl32(u0, u2); \
      pl32(u1, u3); \
      union { unsigned u[4]; v8s v; } pf; \
      pf.u[0] = u0; pf.u[1] = u1; pf.u[2] = u2; pf.u[3] = u3; \
      _Pragma("unroll") \
      for (int db = 0; db < 2; ++db) { \
        int r = db * 32 + q31; \
        v8s vf = *(const v8s*)(vbase + (BOFS) + r * 64 + (((s * 2 + hf) ^ (r & 7)) << 3)); \
        acc[db] = __builtin_amdgcn_mfma_f32_32x32x16_bf16(vf, pf.v, acc[db], 0, 0, 0); \
      } \
    } \
    __builtin_amdgcn_s_setprio(0); \
  } while (0)

  STAGE(tb, 0);
  #pragma unroll 1
  for (int k2 = 0; k2 < 16; ++k2) {
    int kt = k2 * 2;
    STAGE(tb + kt + 1, 1);
    VMW(2); BAR();
    ATILE(0);
    BAR();
    if (kt + 2 < 32) { STAGE(tb + kt + 2, 0); VMW(2); } else { VMW(0); }
    BAR();
    ATILE(4096);
    BAR();
  }
  #undef STAGE
  #undef ATILE

  // ---- write unnormalized partial O + (M, L) ----
  int rowg = ((z * 16 + bh) << 12) + qt * 256 + w * 32 + q31;
  #pragma unroll
  for (int db = 0; db < 2; ++db)
    #pragma unroll
    for (int r4 = 0; r4 < 4; ++r4) {
      v4s o;
      #pragma unroll
      for (int j = 0; j < 4; ++j) o[j] = f2bs(acc[db][r4 * 4 + j]);
      *(v4s*)(pO + (size_t)rowg * 64 + db * 32 + r4 * 8 + hf * 4) = o;
    }
  if (hf == 0) { pm[rowg] = m; pl[rowg] = ls; }
}

// ---------------- K3b: merge the 2 kv-half partials -> ctx bf16
__global__ __launch_bounds__(256)
void k_amerge(const short* __restrict__ pO, const float* __restrict__ pm,
              const float* __restrict__ pl, short* __restrict__ ctx) {
  int idx = blockIdx.x * 256 + threadIdx.x;   // 524288 total
  int row = idx >> 3, c8 = (idx & 7) * 8;
  int bh = row >> 12, n = row & 4095;
  int b = bh >> 2, h = bh & 3;
  float mA = pm[row], mB = pm[65536 + row];
  float lA = pl[row], lB = pl[65536 + row];
  float M = fmaxf(mA, mB);
  float wA = fexp2(mA - M), wB = fexp2(mB - M);
  float rc = 1.0f / (lA * wA + lB * wB);
  v8s a = *(const v8s*)(pO + (size_t)row * 64 + c8);
  v8s bb = *(const v8s*)(pO + ((size_t)(65536 + row)) * 64 + c8);
  v8s o;
  #pragma unroll
  for (int j = 0; j < 8; ++j)
    o[j] = f2bs((bs2f(a[j]) * wA + bs2f(bb[j]) * wB) * rc);
  *(v8s*)(ctx + (size_t)(b * NN + n) * ND + h * 64 + c8) = o;
}

// ---------------- K4: out-proj GEMM (M=16384,K=256,N=256) -> hbuf[:, 256:512]
__global__ __launch_bounds__(256)
void k_oproj(const short* __restrict__ ctx, const short* __restrict__ Wb,
             const float* __restrict__ bias, short* __restrict__ hbuf) {
  __shared__ short Al[2][2048];
  __shared__ short Bl[2][2048];
  int mt = blockIdx.x, nt = blockIdx.y, tid = threadIdx.x;
  int w = tid >> 6, lane = tid & 63, lg = lane >> 4, lr = lane & 15;
  int srow = tid >> 2, sc = tid & 3;
  int scol = ((sc ^ (srow & 3)) << 3);
  const short* asrc = ctx + (size_t)(mt * 64 + srow) * 256 + scol;
  const short* bsrc = Wb + (size_t)(nt * 64 + srow) * 256 + scol;
  v4f acc[4] = {};
  int ar = w * 16 + lr;
  int aoff = ar * 32 + ((lg * 8) ^ ((ar & 3) << 3));

#define G_STAGE(kt, b) do { \
    gload16(asrc + (kt) * 32, &Al[b][w * 512]); \
    gload16(bsrc + (kt) * 32, &Bl[b][w * 512]); \
  } while (0)
#define G_COMP(b) do { \
    v8s af = *(const v8s*)(&Al[b][aoff]); \
    _Pragma("unroll") \
    for (int c = 0; c < 4; ++c) { \
      int br = c * 16 + lr; \
      v8s bf = *(const v8s*)(&Bl[b][br * 32 + ((lg * 8) ^ ((br & 3) << 3))]); \
      acc[c] = __builtin_amdgcn_mfma_f32_16x16x32_bf16(af, bf, acc[c], 0, 0, 0); \
    } \
  } while (0)

  G_STAGE(0, 0);
  #pragma unroll 1
  for (int k2 = 0; k2 < 4; ++k2) {
    int kt = k2 * 2;
    G_STAGE(kt + 1, 1);
    VMW(2); BAR();
    G_COMP(0);
    BAR();
    if (kt + 2 < 8) { G_STAGE(kt + 2, 0); VMW(2); } else { VMW(0); }
    BAR();
    G_COMP(1);
    BAR();
  }
#undef G_STAGE
#undef G_COMP

  #pragma unroll
  for (int c = 0; c < 4; ++c) {
    int gcol = nt * 64 + c * 16 + lr;
    float bb = bias[gcol];
    #pragma unroll
    for (int j = 0; j < 4; ++j) {
      int grow = mt * 64 + w * 16 + lg * 4 + j;
      hbuf[(size_t)grow * 512 + 256 + gcol] = f2bs(acc[c][j] + bb);
    }
  }
}

// ---------------- K5: ffn1 v2: 8 waves, 64x512/block, swapped-operand MFMA + cheap LN
__global__ __launch_bounds__(512)
void k_ffn1(const short* __restrict__ hbuf, const short* __restrict__ Wb,
            const float* __restrict__ bias, const float* __restrict__ ln_g,
            const float* __restrict__ ln_b, short* __restrict__ h2) {
  __shared__ short Al[2][2048];
  __shared__ short Bl[2][16384];
  __shared__ float red[64][16];
  int mt = blockIdx.x, tid = threadIdx.x;
  int w = tid >> 6, lane = tid & 63, lg = lane >> 4, lr = lane & 15;
  int srow = tid >> 2, sc = tid & 3;
  int scol = ((sc ^ (srow & 3)) << 3);
  const short* asrc = hbuf + (size_t)(mt * 64 + srow) * 512 + scol;
  const short* bsrc = Wb + (size_t)srow * 512 + scol;
  v4f acc[4][4] = {};

#define F1_STAGE(kt, b) do { \
    if (w < 4) gload16(asrc + (kt) * 32, &Al[b][w * 512]); \
    _Pragma("unroll") \
    for (int i = 0; i < 4; ++i) \
      gload16(bsrc + (size_t)i * 65536 + (kt) * 32, &Bl[b][i * 4096 + w * 512]); \
  } while (0)
#define F1_VMW() do { \
    if (w < 4) { asm volatile("s_waitcnt vmcnt(5)" ::: "memory"); } \
    else       { asm volatile("s_waitcnt vmcnt(4)" ::: "memory"); } \
  } while (0)
#define F1_COMP(b) do { \
    v8s af[4]; \
    _Pragma("unroll") \
    for (int mi = 0; mi < 4; ++mi) { \
      int ar = mi * 16 + lr; \
      af[mi] = *(const v8s*)(&Al[b][ar * 32 + ((lg * 8) ^ ((ar & 3) << 3))]); \
    } \
    _Pragma("unroll") \
    for (int ni = 0; ni < 4; ++ni) { \
      int br = w * 64 + ni * 16 + lr; \
      v8s bf = *(const v8s*)(&Bl[b][br * 32 + ((lg * 8) ^ ((br & 3) << 3))]); \
      _Pragma("unroll") \
      for (int mi = 0; mi < 4; ++mi) \
        acc[mi][ni] = __builtin_amdgcn_mfma_f32_16x16x32_bf16(bf, af[mi], acc[mi][ni], 0, 0, 0); \
    } \
  } while (0)

  F1_STAGE(0, 0);
  #pragma unroll 1
  for (int k2 = 0; k2 < 8; ++k2) {
    int kt = k2 * 2;
    F1_STAGE(kt + 1, 1);
    F1_VMW(); BAR();
    F1_COMP(0);
    BAR();
    if (kt + 2 < 16) { F1_STAGE(kt + 2, 0); F1_VMW(); } else { VMW(0); }
    BAR();
    F1_COMP(1);
    BAR();
  }
#undef F1_STAGE
#undef F1_VMW
#undef F1_COMP

  #pragma unroll
  for (int ni = 0; ni < 4; ++ni) {
    v4f bb = *(const v4f*)(bias + w * 64 + ni * 16 + lg * 4);
    #pragma unroll
    for (int mi = 0; mi < 4; ++mi)
      #pragma unroll
      for (int j = 0; j < 4; ++j) acc[mi][ni][j] += bb[j];
  }
  float ps[4], qs[4];
  #pragma unroll
  for (int mi = 0; mi < 4; ++mi) {
    float p = 0.f, q = 0.f;
    #pragma unroll
    for (int ni = 0; ni < 4; ++ni)
      #pragma unroll
      for (int j = 0; j < 4; ++j) { float v = acc[mi][ni][j]; p += v; q += v * v; }
    p += __shfl_xor(p, 16, 64); q += __shfl_xor(q, 16, 64);
    p += __shfl_xor(p, 32, 64); q += __shfl_xor(q, 32, 64);
    ps[mi] = p; qs[mi] = q;
  }
  if (lane < 16) {
    #pragma unroll
    for (int mi = 0; mi < 4; ++mi) {
      red[mi * 16 + lane][w * 2] = ps[mi];
      red[mi * 16 + lane][w * 2 + 1] = qs[mi];
    }
  }
  __syncthreads();
  float mus[4], rss[4];
  #pragma unroll
  for (int mi = 0; mi < 4; ++mi) {
    int row = mi * 16 + lr;
    v4f r0 = *(const v4f*)&red[row][0];
    v4f r1 = *(const v4f*)&red[row][4];
    v4f r2 = *(const v4f*)&red[row][8];
    v4f r3 = *(const v4f*)&red[row][12];
    float sum = r0[0] + r0[2] + r1[0] + r1[2] + r2[0] + r2[2] + r3[0] + r3[2];
    float sq  = r0[1] + r0[3] + r1[1] + r1[3] + r2[1] + r2[3] + r3[1] + r3[3];
    float mu = sum * (1.0f / 512.0f);
    float var = sq * (1.0f / 512.0f) - mu * mu;
    mus[mi] = mu;
    rss[mi] = rsqrtf(var + 1e-5f);
  }
  #pragma unroll
  for (int ni = 0; ni < 4; ++ni) {
    int cb = w * 64 + ni * 16 + lg * 4;
    v4f g4 = *(const v4f*)(ln_g + cb);
    v4f b4 = *(const v4f*)(ln_b + cb);
    #pragma unroll
    for (int mi = 0; mi < 4; ++mi) {
      int grow = mt * 64 + mi * 16 + lr;
      v4s o;
      #pragma unroll
      for (int j = 0; j < 4; ++j) {
        float y = (acc[mi][ni][j] - mus[mi]) * rss[mi] * g4[j] + b4[j];
        float z = 0.7978845608f * (y + 0.044715f * y * y * y);
        float e = fexp2(2.88539008178f * z);
        float t = (e - 1.0f) * __builtin_amdgcn_rcpf(e + 1.0f);
        o[j] = f2bs_fast(0.5f * y * (1.0f + t));
      }
      *(v4s*)(h2 + (size_t)grow * 512 + cb) = o;
    }
  }
}

// ---------------- K6: ffn2 GEMM (M=16384,K=512,N=256) + bias + residual -> out fp32
__global__ __launch_bounds__(256)
void k_ffn2(const short* __restrict__ h2, const short* __restrict__ Wb,
             const float* __restrict__ bias, const float* __restrict__ desc,
             float* __restrict__ out) {
  __shared__ short Al[2][2048];
  __shared__ short Bl[2][2048];
  int mt = blockIdx.x, nt = blockIdx.y, tid = threadIdx.x;
  int w = tid >> 6, lane = tid & 63, lg = lane >> 4, lr = lane & 15;
  int srow = tid >> 2, sc = tid & 3;
  int scol = ((sc ^ (srow & 3)) << 3);
  const short* asrc = h2 + (size_t)(mt * 64 + srow) * 512 + scol;
  const short* bsrc = Wb + (size_t)(nt * 64 + srow) * 512 + scol;
  v4f acc[4] = {};
  int ar = w * 16 + lr;
  int aoff = ar * 32 + ((lg * 8) ^ ((ar & 3) << 3));

#define G_STAGE(kt, b) do { \
    gload16(asrc + (kt) * 32, &Al[b][w * 512]); \
    gload16(bsrc + (kt) * 32, &Bl[b][w * 512]); \
  } while (0)
#define G_COMP(b) do { \
    v8s af = *(const v8s*)(&Al[b][aoff]); \
    _Pragma("unroll") \
    for (int c = 0; c < 4; ++c) { \
      int br = c * 16 + lr; \
      v8s bf = *(const v8s*)(&Bl[b][br * 32 + ((lg * 8) ^ ((br & 3) << 3))]); \
      acc[c] = __builtin_amdgcn_mfma_f32_16x16x32_bf16(af, bf, acc[c], 0, 0, 0); \
    } \
  } while (0)

  G_STAGE(0, 0);
  #pragma unroll 1
  for (int k2 = 0; k2 < 8; ++k2) {
    int kt = k2 * 2;
    G_STAGE(kt + 1, 1);
    VMW(2); BAR();
    G_COMP(0);
    BAR();
    if (kt + 2 < 16) { G_STAGE(kt + 2, 0); VMW(2); } else { VMW(0); }
    BAR();
    G_COMP(1);
    BAR();
  }
#undef G_STAGE
#undef G_COMP

  #pragma unroll
  for (int c = 0; c < 4; ++c) {
    int gcol = nt * 64 + c * 16 + lr;
    float bb = bias[gcol];
    #pragma unroll
    for (int j = 0; j < 4; ++j) {
      int grow = mt * 64 + w * 16 + lg * 4 + j;
      out[(size_t)grow * 256 + gcol] = desc[(size_t)grow * 256 + gcol] + acc[c][j] + bb;
    }
  }
}

extern "C" void kernel_launch(void* const* d_in, const int* in_sizes, int n_in,
                              void* d_out, int out_size, void* d_ws, size_t ws_size,
                              hipStream_t stream) {
  const float* desc   = (const float*)d_in[0];
  const float* kp     = (const float*)d_in[1];
  const float* Wqkv_w = (const float*)d_in[2];
  const float* Wqkv_b = (const float*)d_in[3];
  const float* out_w  = (const float*)d_in[4];
  const float* out_b  = (const float*)d_in[5];
  const float* ffn1_w = (const float*)d_in[6];
  const float* ffn1_b = (const float*)d_in[7];
  const float* ln_g   = (const float*)d_in[8];
  const float* ln_b   = (const float*)d_in[9];
  const float* ffn2_w = (const float*)d_in[10];
  const float* ffn2_b = (const float*)d_in[11];
  float* out = (float*)d_out;
  char* ws = (char*)d_ws;

  const size_t MB = 1024 * 1024;
  short* hbuf = (short*)(ws);                 // [16384][512] bf16 (desc | message)
  short* Qb   = (short*)(ws + 16 * MB);       // [B,H,N,64]
  short* Kb   = (short*)(ws + 24 * MB);
  short* Vt   = (short*)(ws + 32 * MB);       // [B,H,64,N] (transposed V)
  short* ctxb = (short*)(ws + 40 * MB);       // [16384][256]
  short* h2   = (short*)(ws + 16 * MB);       // reuses Qb/Kb (dead after attn)
  short* wbuf = (short*)(ws + 48 * MB);       // bf16 weights: 1.25MB
  short* wq = wbuf;                           // [768][256]
  short* wo = wbuf + 196608;                  // [256][256]
  short* w1 = wbuf + 262144;                  // [512][512]
  short* w2 = wbuf + 524288;                  // [256][512]
  short* pO = (short*)(ws + 50 * MB);         // [2][16][4096][64] bf16 partial O : 16MB
  float* pm = (float*)(ws + 66 * MB);         // [2][65536] fp32 : 512KB
  float* pl = (float*)(ws + 66 * MB + 524288);// [2][65536] fp32 : 512KB

  k_wcast <<<dim3(320),        dim3(256), 0, stream>>>(Wqkv_w, out_w, ffn1_w, ffn2_w, wbuf);
  k_cast  <<<dim3(4096),       dim3(256), 0, stream>>>(desc, hbuf);
  k_qkv   <<<dim3(256, 12),    dim3(256), 0, stream>>>(hbuf, wq, Wqkv_b, kp, Qb, Kb, Vt);
  k_attn  <<<dim3(16, 16, 2),  dim3(512), 0, stream>>>(Qb, Kb, Vt, pO, pm, pl);
  k_amerge<<<dim3(2048),       dim3(256), 0, stream>>>(pO, pm, pl, ctxb);
  k_oproj <<<dim3(256, 4),     dim3(256), 0, stream>>>(ctxb, wo, out_b, hbuf);
  k_ffn1  <<<dim3(256),        dim3(512), 0, stream>>>(hbuf, w1, ffn1_b, ln_g, ln_b, h2);
  k_ffn2  <<<dim3(256, 4),     dim3(256), 0, stream>>>(h2, w2, ffn2_b, desc, out);
}

// Round 12
// 132.357 us; speedup vs baseline: 5.9192x; 1.2867x over previous
//
#include <hip/hip_runtime.h>
#include <hip/hip_bf16.h>

typedef __attribute__((ext_vector_type(8))) short v8s;
typedef __attribute__((ext_vector_type(4))) short v4s;
typedef __attribute__((ext_vector_type(4))) float v4f;
typedef __attribute__((ext_vector_type(8))) float v8f;
typedef __attribute__((ext_vector_type(16))) float v16f;

#define NB 4
#define NN 4096
#define ND 256
#define NH 4
#define NHD 64

__device__ __forceinline__ short f2bs(float f) {
  union { __hip_bfloat16 h; short s; } u;
  u.h = __float2bfloat16(f);
  return u.s;
}
__device__ __forceinline__ float bs2f(short s) {
  union { short s; __hip_bfloat16 h; } u;
  u.s = s;
  return __bfloat162float(u.h);
}
__device__ __forceinline__ short f2bs_fast(float f) {
  unsigned u = __float_as_uint(f);
  return (short)((u + 0x7fffu + ((u >> 16) & 1u)) >> 16);
}
__device__ __forceinline__ float fexp2(float x) {
#if __has_builtin(__builtin_amdgcn_exp2f)
  return __builtin_amdgcn_exp2f(x);
#else
  return exp2f(x);
#endif
}
__device__ __forceinline__ unsigned cvt_pk(float lo, float hi) {
  unsigned r;
  asm("v_cvt_pk_bf16_f32 %0, %1, %2" : "=v"(r) : "v"(lo), "v"(hi));
  return r;
}
__device__ __forceinline__ void pl32(unsigned &a, unsigned &b) {
  asm("v_permlane32_swap_b32 %0, %1" : "+v"(a), "+v"(b));
}
__device__ __forceinline__ float xpick(float x, int hf) {
  unsigned t = __float_as_uint(x), u = t;
  pl32(t, u);
  return __uint_as_float(hf ? t : u);
}

__device__ __forceinline__ void gload16(const short* g, short* l) {
  __builtin_amdgcn_global_load_lds((const __attribute__((address_space(1))) void*)g,
                                   (__attribute__((address_space(3))) void*)l, 16, 0, 0);
}

#define VMW(n) asm volatile("s_waitcnt vmcnt(" #n ")" ::: "memory")
#define BAR()  { __builtin_amdgcn_s_barrier(); __builtin_amdgcn_sched_barrier(0); }

// ---------------- K0: cast descriptors fp32 -> bf16 into hbuf[:, 0:256] (ld 512)
__global__ void k_cast(const float* __restrict__ desc, short* __restrict__ hbuf) {
  int i = blockIdx.x * blockDim.x + threadIdx.x;
  const v4f* src = (const v4f*)desc;
  v4f v = src[i];
  int e0 = i << 2;
  int row = e0 >> 8;
  int col = e0 & 255;
  v4s o;
  #pragma unroll
  for (int j = 0; j < 4; ++j) o[j] = f2bs(v[j]);
  *(v4s*)(hbuf + row * 512 + col) = o;
}

// ---------------- K0b: cast weights fp32 -> bf16 (Wqkv | out_w | ffn1_w | ffn2_w)
__global__ void k_wcast(const float* __restrict__ a, const float* __restrict__ b,
                        const float* __restrict__ c, const float* __restrict__ d,
                        short* __restrict__ o) {
  int i = (blockIdx.x * 256 + threadIdx.x) * 8;
  const float* s; int off;
  if (i < 196608)      { s = a; off = 0; }
  else if (i < 262144) { s = b; off = 196608; }
  else if (i < 524288) { s = c; off = 262144; }
  else                 { s = d; off = 524288; }
  v8f v = *(const v8f*)(s + (i - off));
  v8s r;
  #pragma unroll
  for (int j = 0; j < 8; ++j) r[j] = f2bs(v[j]);
  *(v8s*)(o + i) = r;
}

// ---------------- K1: QKV GEMM 128x128 tiles + fused RoPE (permuted col order)
// grid (128, 6): mt rows 128, nt = 128-col group; t = nt>>1 (block-uniform).
__global__ __launch_bounds__(256)
void k_qkv(const short* __restrict__ hbuf, const short* __restrict__ Wb,
           const float* __restrict__ bias, const float* __restrict__ kp,
           short* __restrict__ Qb, short* __restrict__ Kb, short* __restrict__ Vt) {
  __shared__ short Al[2][4096];
  __shared__ short Bl[2][4096];
  int mt = blockIdx.x, nt = blockIdx.y, tid = threadIdx.x;
  int w = tid >> 6, lane = tid & 63, lg = lane >> 4, lr = lane & 15;
  int t_ = nt >> 1;
  int mb = (w >> 1) * 64, nb = (w & 1) * 64;
  // staging: 512 slots each for A and B; thread covers slots tid and tid+256
  int s0 = tid, s1 = tid + 256;
  int r0 = s0 >> 2, c0 = s0 & 3, r1 = s1 >> 2, c1 = s1 & 3;
  int sc0 = ((c0 ^ (r0 & 3)) << 3), sc1 = ((c1 ^ (r1 & 3)) << 3);
  const short* asrc0 = hbuf + (size_t)(mt * 128 + r0) * 512 + sc0;
  const short* asrc1 = hbuf + (size_t)(mt * 128 + r1) * 512 + sc1;
  int vc0 = nt * 128 + r0, vc1 = nt * 128 + r1;
  int wr0 = ((vc0 >> 6) & 3) * 192 + (vc0 & 63) * 3 + t_;
  int wr1 = ((vc1 >> 6) & 3) * 192 + (vc1 & 63) * 3 + t_;
  const short* bsrc0 = Wb + (size_t)wr0 * 256 + sc0;
  const short* bsrc1 = Wb + (size_t)wr1 * 256 + sc1;
  v4f acc[4][4] = {};
  int asw = ((lg ^ (lr & 3)) << 3);

#define G_STAGE(kt, b) do { \
    gload16(asrc0 + (kt) * 32, &Al[b][s0 * 8]); \
    gload16(asrc1 + (kt) * 32, &Al[b][s1 * 8]); \
    gload16(bsrc0 + (kt) * 32, &Bl[b][s0 * 8]); \
    gload16(bsrc1 + (kt) * 32, &Bl[b][s1 * 8]); \
  } while (0)
#define G_COMP(b) do { \
    v8s af[4], bf[4]; \
    _Pragma("unroll") \
    for (int mi = 0; mi < 4; ++mi) \
      af[mi] = *(const v8s*)(&Al[b][(mb + mi * 16 + lr) * 32 + asw]); \
    _Pragma("unroll") \
    for (int ni = 0; ni < 4; ++ni) \
      bf[ni] = *(const v8s*)(&Bl[b][(nb + ni * 16 + lr) * 32 + asw]); \
    _Pragma("unroll") \
    for (int ni = 0; ni < 4; ++ni) \
      _Pragma("unroll") \
      for (int mi = 0; mi < 4; ++mi) \
        acc[mi][ni] = __builtin_amdgcn_mfma_f32_16x16x32_bf16(af[mi], bf[ni], acc[mi][ni], 0, 0, 0); \
  } while (0)

  G_STAGE(0, 0);
  #pragma unroll 1
  for (int k2 = 0; k2 < 4; ++k2) {
    int kt = k2 * 2;
    G_STAGE(kt + 1, 1);
    VMW(4); BAR();
    G_COMP(0);
    BAR();
    if (kt + 2 < 8) { G_STAGE(kt + 2, 0); VMW(4); } else { VMW(0); }
    BAR();
    G_COMP(1);
    BAR();
  }
#undef G_STAGE
#undef G_COMP

  float qsc = (t_ == 0) ? 0.125f * 1.44269504088896340736f : 1.0f;
  #pragma unroll
  for (int ni = 0; ni < 4; ++ni) {
    int vc = nt * 128 + nb + ni * 16 + lr;
    int h_ = (vc >> 6) & 3, d = vc & 63;
    float bb = bias[h_ * 192 + d * 3 + t_];
    #pragma unroll
    for (int mi = 0; mi < 4; ++mi) {
      int grow0 = mt * 128 + mb + mi * 16 + lg * 4;
      int b_ = grow0 >> 12, n0 = grow0 & 4095;
      if (t_ == 2) {
        v4s pw;
        #pragma unroll
        for (int j = 0; j < 4; ++j) pw[j] = f2bs(acc[mi][ni][j] + bb);
        *(v4s*)(Vt + ((size_t)((b_ * NH + h_) * NHD + d) * NN + n0)) = pw;
      } else {
        short* dst = (t_ == 0) ? Qb : Kb;
        #pragma unroll
        for (int j = 0; j < 4; ++j) {
          float x = acc[mi][ni][j] + bb;
          float xp = __shfl_xor(x, 1, 64);
          int n_ = n0 + j;
          float cs = kp[((size_t)b_ * NN + n_) * 64 + d];
          float sn = kp[((size_t)(NB + b_) * NN + n_) * 64 + d];
          float ov = (d & 1) ? (x * cs + xp * sn) : (x * cs - xp * sn);
          dst[((size_t)((b_ * NH + h_) * NN + n_)) * 64 + d] = f2bs(ov * qsc);
        }
      }
    }
  }
}

// ---------------- K3: flash attention (round-8 version, best measured). grid (16,16), 16 waves.
__global__ __launch_bounds__(1024)
void k_attn(const short* __restrict__ Qb, const short* __restrict__ Kb,
            const short* __restrict__ Vt, short* __restrict__ ctx) {
  __shared__ char pool[72192];
  int qt = blockIdx.x, bh = blockIdx.y;
  int b = bh >> 2, h = bh & 3;
  const short* Qp = Qb + (size_t)bh * NN * NHD;
  const short* Kp = Kb + (size_t)bh * NN * NHD;
  const short* Vp = Vt + (size_t)bh * NHD * NN;
  int tid = threadIdx.x, w = tid >> 6, lane = tid & 63;
  int g = w >> 3, w8 = w & 7;
  int q31 = lane & 31, hf = lane >> 5;
  const float THR = 11.5416f;

  v8s qf[4];
  {
    int qrow = qt * 256 + w8 * 32 + q31;
    #pragma unroll
    for (int kd = 0; kd < 4; ++kd)
      qf[kd] = *(const v8s*)(Qp + (size_t)qrow * 64 + kd * 16 + hf * 8);
  }
  float m = -3.0e38f, ls = 0.f;
  v16f acc[2] = {};

  int slot = w8 * 64 + lane;
  int r0 = slot >> 3, c0 = slot & 7;
  int ko0 = r0 * 64 + ((c0 ^ (r0 & 7)) << 3);
  size_t vo0 = (size_t)r0 * NN + ((c0 ^ (r0 & 7)) << 3);
  int tb = g * 32;
  const short* kbase = (const short*)(pool + g * 32768);
  const short* vbase = (const short*)(pool + g * 32768 + 16384);

  #define STAGE(t, bfi) do { \
    gload16(Kp + (size_t)(t) * 4096 + ko0, (short*)(pool + g * 32768 + (bfi) * 8192) + w8 * 512); \
    gload16(Vp + (size_t)(t) * 64 + vo0, (short*)(pool + g * 32768 + 16384 + (bfi) * 8192) + w8 * 512); \
  } while (0)

  #define ATILE(BOFS) do { \
    v16f st[2]; \
    __builtin_amdgcn_s_setprio(1); \
    _Pragma("unroll") \
    for (int kvb = 0; kvb < 2; ++kvb) { \
      int r = kvb * 32 + q31; \
      int sw = r & 7; \
      v16f zz = {}; \
      _Pragma("unroll") \
      for (int kd = 0; kd < 4; ++kd) { \
        v8s kf = *(const v8s*)(kbase + (BOFS) + r * 64 + (((kd * 2 + hf) ^ sw) << 3)); \
        zz = __builtin_amdgcn_mfma_f32_32x32x16_bf16(kf, qf[kd], zz, 0, 0, 0); \
      } \
      st[kvb] = zz; \
    } \
    __builtin_amdgcn_s_setprio(0); \
    float mx[8]; \
    _Pragma("unroll") \
    for (int i = 0; i < 8; ++i) \
      mx[i] = fmaxf(fmaxf(st[0][i], st[0][i + 8]), fmaxf(st[1][i], st[1][i + 8])); \
    _Pragma("unroll") \
    for (int off = 4; off >= 1; off >>= 1) \
      _Pragma("unroll") \
      for (int i = 0; i < off; ++i) mx[i] = fmaxf(mx[i], mx[i + off]); \
    float pmax = fmaxf(mx[0], xpick(mx[0], hf)); \
    if (__any(pmax - m > THR)) { \
      float mn = fmaxf(m, pmax); \
      float rr = fexp2(m - mn); \
      m = mn; \
      _Pragma("unroll") \
      for (int db = 0; db < 2; ++db) \
        _Pragma("unroll") \
        for (int r = 0; r < 16; ++r) acc[db][r] *= rr; \
      ls *= rr; \
    } \
    _Pragma("unroll") \
    for (int kvb = 0; kvb < 2; ++kvb) \
      _Pragma("unroll") \
      for (int r = 0; r < 16; ++r) st[kvb][r] = fexp2(st[kvb][r] - m); \
    float sm[8]; \
    _Pragma("unroll") \
    for (int i = 0; i < 8; ++i) \
      sm[i] = (st[0][i] + st[0][i + 8]) + (st[1][i] + st[1][i + 8]); \
    _Pragma("unroll") \
    for (int off = 4; off >= 1; off >>= 1) \
      _Pragma("unroll") \
      for (int i = 0; i < off; ++i) sm[i] += sm[i + off]; \
    ls += sm[0] + xpick(sm[0], hf); \
    __builtin_amdgcn_s_setprio(1); \
    _Pragma("unroll") \
    for (int s = 0; s < 4; ++s) { \
      int kvb = s >> 1, rb = (s & 1) * 8; \
      unsigned u0 = cvt_pk(st[kvb][rb + 0], st[kvb][rb + 1]); \
      unsigned u1 = cvt_pk(st[kvb][rb + 2], st[kvb][rb + 3]); \
      unsigned u2 = cvt_pk(st[kvb][rb + 4], st[kvb][rb + 5]); \
      unsigned u3 = cvt_pk(st[kvb][rb + 6], st[kvb][rb + 7]); \
      pl32(u0, u2); \
      pl32(u1, u3); \
      union { unsigned u[4]; v8s v; } pf; \
      pf.u[0] = u0; pf.u[1] = u1; pf.u[2] = u2; pf.u[3] = u3; \
      _Pragma("unroll") \
      for (int db = 0; db < 2; ++db) { \
        int r = db * 32 + q31; \
        v8s vf = *(const v8s*)(vbase + (BOFS) + r * 64 + (((s * 2 + hf) ^ (r & 7)) << 3)); \
        acc[db] = __builtin_amdgcn_mfma_f32_32x32x16_bf16(vf, pf.v, acc[db], 0, 0, 0); \
      } \
    } \
    __builtin_amdgcn_s_setprio(0); \
  } while (0)

  STAGE(tb, 0);
  #pragma unroll 1
  for (int k2 = 0; k2 < 8; ++k2) {
    int kt = k2 * 2;
    STAGE(tb + kt + 1, 1);
    VMW(2); BAR();
    ATILE(0);
    BAR();
    if (kt + 2 < 16) { STAGE(tb + kt + 2, 0); VMW(2); } else { VMW(0); }
    BAR();
    ATILE(4096);
    BAR();
  }
  #undef STAGE
  #undef ATILE

  // ---- in-block merge of the two kv-half groups via LDS ----
  float* marr = (float*)pool;
  float* mlm  = (float*)(pool + 69632);
  float* mll  = (float*)(pool + 70656);
  int ql = w8 * 32 + q31;
  __syncthreads();
  if (g == 0) {
    #pragma unroll
    for (int db = 0; db < 2; ++db)
      #pragma unroll
      for (int r4 = 0; r4 < 4; ++r4) {
        v4f q_;
        #pragma unroll
        for (int j = 0; j < 4; ++j) q_[j] = acc[db][r4 * 4 + j];
        *(v4f*)&marr[ql * 68 + db * 32 + r4 * 8 + hf * 4] = q_;
      }
    if (hf == 0) { mlm[ql] = m; mll[ql] = ls; }
  }
  __syncthreads();
  if (g == 1) {
    float mA = mlm[ql], lsA = mll[ql];
    float M = fmaxf(mA, m);
    float wA = fexp2(mA - M), wB = fexp2(m - M);
    float rc = __builtin_amdgcn_rcpf(lsA * wA + ls * wB);
    int n = qt * 256 + ql;
    #pragma unroll
    for (int db = 0; db < 2; ++db)
      #pragma unroll
      for (int r4 = 0; r4 < 4; ++r4) {
        v4f a = *(v4f*)&marr[ql * 68 + db * 32 + r4 * 8 + hf * 4];
        v4s o;
        #pragma unroll
        for (int j = 0; j < 4; ++j)
          o[j] = f2bs((a[j] * wA + acc[db][r4 * 4 + j] * wB) * rc);
        *(v4s*)(ctx + (size_t)(b * NN + n) * ND + h * 64 + db * 32 + r4 * 8 + hf * 4) = o;
      }
  }
}

// ---------------- K4: out-proj GEMM 128x128 (M=16384,K=256,N=256) -> hbuf[:, 256:512]
__global__ __launch_bounds__(256)
void k_oproj(const short* __restrict__ ctx, const short* __restrict__ Wb,
             const float* __restrict__ bias, short* __restrict__ hbuf) {
  __shared__ short Al[2][4096];
  __shared__ short Bl[2][4096];
  int mt = blockIdx.x, nt = blockIdx.y, tid = threadIdx.x;
  int w = tid >> 6, lane = tid & 63, lg = lane >> 4, lr = lane & 15;
  int mb = (w >> 1) * 64, nb = (w & 1) * 64;
  int s0 = tid, s1 = tid + 256;
  int r0 = s0 >> 2, c0 = s0 & 3, r1 = s1 >> 2, c1 = s1 & 3;
  int sc0 = ((c0 ^ (r0 & 3)) << 3), sc1 = ((c1 ^ (r1 & 3)) << 3);
  const short* asrc0 = ctx + (size_t)(mt * 128 + r0) * 256 + sc0;
  const short* asrc1 = ctx + (size_t)(mt * 128 + r1) * 256 + sc1;
  const short* bsrc0 = Wb + (size_t)(nt * 128 + r0) * 256 + sc0;
  const short* bsrc1 = Wb + (size_t)(nt * 128 + r1) * 256 + sc1;
  v4f acc[4][4] = {};
  int asw = ((lg ^ (lr & 3)) << 3);

#define G_STAGE(kt, b) do { \
    gload16(asrc0 + (kt) * 32, &Al[b][s0 * 8]); \
    gload16(asrc1 + (kt) * 32, &Al[b][s1 * 8]); \
    gload16(bsrc0 + (kt) * 32, &Bl[b][s0 * 8]); \
    gload16(bsrc1 + (kt) * 32, &Bl[b][s1 * 8]); \
  } while (0)
#define G_COMP(b) do { \
    v8s af[4], bf[4]; \
    _Pragma("unroll") \
    for (int mi = 0; mi < 4; ++mi) \
      af[mi] = *(const v8s*)(&Al[b][(mb + mi * 16 + lr) * 32 + asw]); \
    _Pragma("unroll") \
    for (int ni = 0; ni < 4; ++ni) \
      bf[ni] = *(const v8s*)(&Bl[b][(nb + ni * 16 + lr) * 32 + asw]); \
    _Pragma("unroll") \
    for (int ni = 0; ni < 4; ++ni) \
      _Pragma("unroll") \
      for (int mi = 0; mi < 4; ++mi) \
        acc[mi][ni] = __builtin_amdgcn_mfma_f32_16x16x32_bf16(af[mi], bf[ni], acc[mi][ni], 0, 0, 0); \
  } while (0)

  G_STAGE(0, 0);
  #pragma unroll 1
  for (int k2 = 0; k2 < 4; ++k2) {
    int kt = k2 * 2;
    G_STAGE(kt + 1, 1);
    VMW(4); BAR();
    G_COMP(0);
    BAR();
    if (kt + 2 < 8) { G_STAGE(kt + 2, 0); VMW(4); } else { VMW(0); }
    BAR();
    G_COMP(1);
    BAR();
  }
#undef G_STAGE
#undef G_COMP

  #pragma unroll
  for (int ni = 0; ni < 4; ++ni) {
    int gcol = nt * 128 + nb + ni * 16 + lr;
    float bb = bias[gcol];
    #pragma unroll
    for (int mi = 0; mi < 4; ++mi) {
      #pragma unroll
      for (int j = 0; j < 4; ++j) {
        int grow = mt * 128 + mb + mi * 16 + lg * 4 + j;
        hbuf[(size_t)grow * 512 + 256 + gcol] = f2bs(acc[mi][ni][j] + bb);
      }
    }
  }
}

// ---------------- K5: ffn1 (round-8 version): 8 waves, 64x512/block, swapped-operand MFMA + cheap LN
__global__ __launch_bounds__(512)
void k_ffn1(const short* __restrict__ hbuf, const short* __restrict__ Wb,
            const float* __restrict__ bias, const float* __restrict__ ln_g,
            const float* __restrict__ ln_b, short* __restrict__ h2) {
  __shared__ short Al[2][2048];
  __shared__ short Bl[2][16384];
  __shared__ float red[64][16];
  int mt = blockIdx.x, tid = threadIdx.x;
  int w = tid >> 6, lane = tid & 63, lg = lane >> 4, lr = lane & 15;
  int srow = tid >> 2, sc = tid & 3;
  int scol = ((sc ^ (srow & 3)) << 3);
  const short* asrc = hbuf + (size_t)(mt * 64 + srow) * 512 + scol;
  const short* bsrc = Wb + (size_t)srow * 512 + scol;
  v4f acc[4][4] = {};

#define F1_STAGE(kt, b) do { \
    if (w < 4) gload16(asrc + (kt) * 32, &Al[b][w * 512]); \
    _Pragma("unroll") \
    for (int i = 0; i < 4; ++i) \
      gload16(bsrc + (size_t)i * 65536 + (kt) * 32, &Bl[b][i * 4096 + w * 512]); \
  } while (0)
#define F1_VMW() do { \
    if (w < 4) { asm volatile("s_waitcnt vmcnt(5)" ::: "memory"); } \
    else       { asm volatile("s_waitcnt vmcnt(4)" ::: "memory"); } \
  } while (0)
#define F1_COMP(b) do { \
    v8s af[4]; \
    _Pragma("unroll") \
    for (int mi = 0; mi < 4; ++mi) { \
      int ar = mi * 16 + lr; \
      af[mi] = *(const v8s*)(&Al[b][ar * 32 + ((lg * 8) ^ ((ar & 3) << 3))]); \
    } \
    _Pragma("unroll") \
    for (int ni = 0; ni < 4; ++ni) { \
      int br = w * 64 + ni * 16 + lr; \
      v8s bf = *(const v8s*)(&Bl[b][br * 32 + ((lg * 8) ^ ((br & 3) << 3))]); \
      _Pragma("unroll") \
      for (int mi = 0; mi < 4; ++mi) \
        acc[mi][ni] = __builtin_amdgcn_mfma_f32_16x16x32_bf16(bf, af[mi], acc[mi][ni], 0, 0, 0); \
    } \
  } while (0)

  F1_STAGE(0, 0);
  #pragma unroll 1
  for (int k2 = 0; k2 < 8; ++k2) {
    int kt = k2 * 2;
    F1_STAGE(kt + 1, 1);
    F1_VMW(); BAR();
    F1_COMP(0);
    BAR();
    if (kt + 2 < 16) { F1_STAGE(kt + 2, 0); F1_VMW(); } else { VMW(0); }
    BAR();
    F1_COMP(1);
    BAR();
  }
#undef F1_STAGE
#undef F1_VMW
#undef F1_COMP

  #pragma unroll
  for (int ni = 0; ni < 4; ++ni) {
    v4f bb = *(const v4f*)(bias + w * 64 + ni * 16 + lg * 4);
    #pragma unroll
    for (int mi = 0; mi < 4; ++mi)
      #pragma unroll
      for (int j = 0; j < 4; ++j) acc[mi][ni][j] += bb[j];
  }
  float ps[4], qs[4];
  #pragma unroll
  for (int mi = 0; mi < 4; ++mi) {
    float p = 0.f, q = 0.f;
    #pragma unroll
    for (int ni = 0; ni < 4; ++ni)
      #pragma unroll
      for (int j = 0; j < 4; ++j) { float v = acc[mi][ni][j]; p += v; q += v * v; }
    p += __shfl_xor(p, 16, 64); q += __shfl_xor(q, 16, 64);
    p += __shfl_xor(p, 32, 64); q += __shfl_xor(q, 32, 64);
    ps[mi] = p; qs[mi] = q;
  }
  if (lane < 16) {
    #pragma unroll
    for (int mi = 0; mi < 4; ++mi) {
      red[mi * 16 + lane][w * 2] = ps[mi];
      red[mi * 16 + lane][w * 2 + 1] = qs[mi];
    }
  }
  __syncthreads();
  float mus[4], rss[4];
  #pragma unroll
  for (int mi = 0; mi < 4; ++mi) {
    int row = mi * 16 + lr;
    v4f r0 = *(const v4f*)&red[row][0];
    v4f r1 = *(const v4f*)&red[row][4];
    v4f r2 = *(const v4f*)&red[row][8];
    v4f r3 = *(const v4f*)&red[row][12];
    float sum = r0[0] + r0[2] + r1[0] + r1[2] + r2[0] + r2[2] + r3[0] + r3[2];
    float sq  = r0[1] + r0[3] + r1[1] + r1[3] + r2[1] + r2[3] + r3[1] + r3[3];
    float mu = sum * (1.0f / 512.0f);
    float var = sq * (1.0f / 512.0f) - mu * mu;
    mus[mi] = mu;
    rss[mi] = rsqrtf(var + 1e-5f);
  }
  #pragma unroll
  for (int ni = 0; ni < 4; ++ni) {
    int cb = w * 64 + ni * 16 + lg * 4;
    v4f g4 = *(const v4f*)(ln_g + cb);
    v4f b4 = *(const v4f*)(ln_b + cb);
    #pragma unroll
    for (int mi = 0; mi < 4; ++mi) {
      int grow = mt * 64 + mi * 16 + lr;
      v4s o;
      #pragma unroll
      for (int j = 0; j < 4; ++j) {
        float y = (acc[mi][ni][j] - mus[mi]) * rss[mi] * g4[j] + b4[j];
        float z = 0.7978845608f * (y + 0.044715f * y * y * y);
        float e = fexp2(2.88539008178f * z);
        float t = (e - 1.0f) * __builtin_amdgcn_rcpf(e + 1.0f);
        o[j] = f2bs_fast(0.5f * y * (1.0f + t));
      }
      *(v4s*)(h2 + (size_t)grow * 512 + cb) = o;
    }
  }
}

// ---------------- K6: ffn2 GEMM 128x128 (M=16384,K=512,N=256) + bias + residual -> out fp32
__global__ __launch_bounds__(256)
void k_ffn2(const short* __restrict__ h2, const short* __restrict__ Wb,
             const float* __restrict__ bias, const float* __restrict__ desc,
             float* __restrict__ out) {
  __shared__ short Al[2][4096];
  __shared__ short Bl[2][4096];
  int mt = blockIdx.x, nt = blockIdx.y, tid = threadIdx.x;
  int w = tid >> 6, lane = tid & 63, lg = lane >> 4, lr = lane & 15;
  int mb = (w >> 1) * 64, nb = (w & 1) * 64;
  int s0 = tid, s1 = tid + 256;
  int r0 = s0 >> 2, c0 = s0 & 3, r1 = s1 >> 2, c1 = s1 & 3;
  int sc0 = ((c0 ^ (r0 & 3)) << 3), sc1 = ((c1 ^ (r1 & 3)) << 3);
  const short* asrc0 = h2 + (size_t)(mt * 128 + r0) * 512 + sc0;
  const short* asrc1 = h2 + (size_t)(mt * 128 + r1) * 512 + sc1;
  const short* bsrc0 = Wb + (size_t)(nt * 128 + r0) * 512 + sc0;
  const short* bsrc1 = Wb + (size_t)(nt * 128 + r1) * 512 + sc1;
  v4f acc[4][4] = {};
  int asw = ((lg ^ (lr & 3)) << 3);

#define G_STAGE(kt, b) do { \
    gload16(asrc0 + (kt) * 32, &Al[b][s0 * 8]); \
    gload16(asrc1 + (kt) * 32, &Al[b][s1 * 8]); \
    gload16(bsrc0 + (kt) * 32, &Bl[b][s0 * 8]); \
    gload16(bsrc1 + (kt) * 32, &Bl[b][s1 * 8]); \
  } while (0)
#define G_COMP(b) do { \
    v8s af[4], bf[4]; \
    _Pragma("unroll") \
    for (int mi = 0; mi < 4; ++mi) \
      af[mi] = *(const v8s*)(&Al[b][(mb + mi * 16 + lr) * 32 + asw]); \
    _Pragma("unroll") \
    for (int ni = 0; ni < 4; ++ni) \
      bf[ni] = *(const v8s*)(&Bl[b][(nb + ni * 16 + lr) * 32 + asw]); \
    _Pragma("unroll") \
    for (int ni = 0; ni < 4; ++ni) \
      _Pragma("unroll") \
      for (int mi = 0; mi < 4; ++mi) \
        acc[mi][ni] = __builtin_amdgcn_mfma_f32_16x16x32_bf16(af[mi], bf[ni], acc[mi][ni], 0, 0, 0); \
  } while (0)

  G_STAGE(0, 0);
  #pragma unroll 1
  for (int k2 = 0; k2 < 8; ++k2) {
    int kt = k2 * 2;
    G_STAGE(kt + 1, 1);
    VMW(4); BAR();
    G_COMP(0);
    BAR();
    if (kt + 2 < 16) { G_STAGE(kt + 2, 0); VMW(4); } else { VMW(0); }
    BAR();
    G_COMP(1);
    BAR();
  }
#undef G_STAGE
#undef G_COMP

  #pragma unroll
  for (int ni = 0; ni < 4; ++ni) {
    int gcol = nt * 128 + nb + ni * 16 + lr;
    float bb = bias[gcol];
    #pragma unroll
    for (int mi = 0; mi < 4; ++mi) {
      #pragma unroll
      for (int j = 0; j < 4; ++j) {
        int grow = mt * 128 + mb + mi * 16 + lg * 4 + j;
        out[(size_t)grow * 256 + gcol] = desc[(size_t)grow * 256 + gcol] + acc[mi][ni][j] + bb;
      }
    }
  }
}

extern "C" void kernel_launch(void* const* d_in, const int* in_sizes, int n_in,
                              void* d_out, int out_size, void* d_ws, size_t ws_size,
                              hipStream_t stream) {
  const float* desc   = (const float*)d_in[0];
  const float* kp     = (const float*)d_in[1];
  const float* Wqkv_w = (const float*)d_in[2];
  const float* Wqkv_b = (const float*)d_in[3];
  const float* out_w  = (const float*)d_in[4];
  const float* out_b  = (const float*)d_in[5];
  const float* ffn1_w = (const float*)d_in[6];
  const float* ffn1_b = (const float*)d_in[7];
  const float* ln_g   = (const float*)d_in[8];
  const float* ln_b   = (const float*)d_in[9];
  const float* ffn2_w = (const float*)d_in[10];
  const float* ffn2_b = (const float*)d_in[11];
  float* out = (float*)d_out;
  char* ws = (char*)d_ws;

  const size_t MB = 1024 * 1024;
  short* hbuf = (short*)(ws);                 // [16384][512] bf16 (desc | message)
  short* Qb   = (short*)(ws + 16 * MB);       // [B,H,N,64]
  short* Kb   = (short*)(ws + 24 * MB);
  short* Vt   = (short*)(ws + 32 * MB);       // [B,H,64,N] (transposed V)
  short* ctxb = (short*)(ws + 40 * MB);       // [16384][256]
  short* h2   = (short*)(ws + 16 * MB);       // reuses Qb/Kb (dead after attn)
  short* wbuf = (short*)(ws + 48 * MB);       // bf16 weights: 1.25MB
  short* wq = wbuf;                           // [768][256]
  short* wo = wbuf + 196608;                  // [256][256]
  short* w1 = wbuf + 262144;                  // [512][512]
  short* w2 = wbuf + 524288;                  // [256][512]

  k_wcast<<<dim3(320),       dim3(256), 0, stream>>>(Wqkv_w, out_w, ffn1_w, ffn2_w, wbuf);
  k_cast <<<dim3(4096),      dim3(256), 0, stream>>>(desc, hbuf);
  k_qkv  <<<dim3(128, 6),    dim3(256), 0, stream>>>(hbuf, wq, Wqkv_b, kp, Qb, Kb, Vt);
  k_attn <<<dim3(16, 16),    dim3(1024), 0, stream>>>(Qb, Kb, Vt, ctxb);
  k_oproj<<<dim3(128, 2),    dim3(256), 0, stream>>>(ctxb, wo, out_b, hbuf);
  k_ffn1 <<<dim3(256),       dim3(512), 0, stream>>>(hbuf, w1, ffn1_b, ln_g, ln_b, h2);
  k_ffn2 <<<dim3(128, 2),    dim3(256), 0, stream>>>(h2, w2, ffn2_b, desc, out);
}